// Round 10
// baseline (7508.721 us; speedup 1.0000x reference)
//
#include <hip/hip_runtime.h>
#include <hip/hip_bf16.h>
#include <math.h>

__device__ inline float bf2f(unsigned short u) { return __uint_as_float(((unsigned)u) << 16); }

// ---------------------------------------------------------------------------
// dtype probe: 1 = bf16 inputs, 0 = f32 inputs.
// ---------------------------------------------------------------------------
__global__ void detect_dtype_k(const unsigned short* __restrict__ src, int* __restrict__ flag) {
  int lane = threadIdx.x & 63;
  unsigned short w = src[2 * lane];
  unsigned e = (w >> 7) & 0xFFu;
  bool inr = (e >= 96u && e <= 130u);
  unsigned long long m = __ballot(inr);
  if (lane == 0) *flag = (__popcll(m) >= 48) ? 1 : 0;
}

// ---------------------------------------------------------------------------
// Generic tiled GEMM: f64 accumulate, f32 STORAGE (emulates an f32 pipeline's
// materialization rounding with deterministic order-free accumulation noise).
// Operand codes: isdin=0 -> f32 workspace; isdin=1 -> d_in (bf16/f32 via flag).
// ---------------------------------------------------------------------------
struct GemmP {
  const int* dflag;
  const void* A; long long aoff; long long sA; int lda; int tA; int adin;
  const void* B; long long boff; long long sB; int ldb; int tB; int bdin;
  const float* A2; int lda2;
  const void* B2; long long b2off; int ldb2; int K2; int b2din;
  const void* bias;            // d_in bias or null
  const float* add; int ldadd; // f32 add or null (may alias C)
  float* C; long long sC; int ldc;
  int M, Nc, K;
  double scale; int relu;
};

__device__ inline double ldop(const void* p, long long idx, int dyn, int isdin) {
  if (isdin)
    return dyn ? (double)bf2f(((const unsigned short*)p)[idx])
               : (double)((const float*)p)[idx];
  return (double)((const float*)p)[idx];
}

__launch_bounds__(256)
__global__ void gemm_fx(GemmP p) {
  __shared__ __align__(16) double As[16][66];
  __shared__ __align__(16) double Bs[16][66];
  int dyn = p.dflag[0];
  int bz = blockIdx.z;
  int row0 = blockIdx.y * 64, col0 = blockIdx.x * 64;
  int tid = threadIdx.x;
  int tm = (tid >> 4) << 2, tn = (tid & 15) << 2;
  int lr = tid >> 2, lk = (tid & 3) << 2;
  int lbn = tid & 63, lbk = tid >> 6;
  double acc[4][4];
#pragma unroll
  for (int i = 0; i < 4; i++)
#pragma unroll
    for (int j = 0; j < 4; j++) acc[i][j] = 0.0;

  for (int seg = 0; seg < 2; seg++) {
    const void* Ap; const void* Bp;
    long long aofs, bofs;
    int lda, ldb, tA, tB, K, adin, bdin;
    if (seg == 0) {
      Ap = p.A; aofs = p.aoff + (long long)bz * p.sA; lda = p.lda; tA = p.tA; adin = p.adin;
      Bp = p.B; bofs = p.boff + (long long)bz * p.sB; ldb = p.ldb; tB = p.tB; bdin = p.bdin;
      K = p.K;
    } else {
      if (!p.A2) break;
      Ap = p.A2; aofs = 0; lda = p.lda2; tA = 0; adin = 0;
      Bp = p.B2; bofs = p.b2off; ldb = p.ldb2; tB = 0; bdin = p.b2din;
      K = p.K2;
    }
    for (int k0 = 0; k0 < K; k0 += 16) {
#pragma unroll
      for (int u = 0; u < 4; u++) {
        int k = k0 + lk + u, m = row0 + lr;
        double v = 0.0;
        if (m < p.M && k < K) {
          long long idx = aofs + (tA ? (long long)k * lda + m : (long long)m * lda + k);
          v = ldop(Ap, idx, dyn, adin);
        }
        As[lk + u][lr] = v;
      }
#pragma unroll
      for (int u = 0; u < 4; u++) {
        int k = k0 + lbk + (u << 2), n = col0 + lbn;
        double v = 0.0;
        if (n < p.Nc && k < K) {
          long long idx = bofs + (tB ? (long long)n * ldb + k : (long long)k * ldb + n);
          v = ldop(Bp, idx, dyn, bdin);
        }
        Bs[lbk + (u << 2)][lbn] = v;
      }
      __syncthreads();
#pragma unroll
      for (int kk = 0; kk < 16; kk++) {
        double a4[4], b4[4];
#pragma unroll
        for (int j = 0; j < 4; j++) { a4[j] = As[kk][tm + j]; b4[j] = Bs[kk][tn + j]; }
#pragma unroll
        for (int i = 0; i < 4; i++)
#pragma unroll
          for (int j = 0; j < 4; j++) acc[i][j] = fma(a4[i], b4[j], acc[i][j]);
      }
      __syncthreads();
    }
  }
  const float* addb = p.add;
  float* Cb = p.C + (long long)bz * p.sC;
#pragma unroll
  for (int i = 0; i < 4; i++) {
    int m = row0 + tm + i;
    if (m >= p.M) continue;
#pragma unroll
    for (int j = 0; j < 4; j++) {
      int n = col0 + tn + j;
      if (n >= p.Nc) continue;
      double v = acc[i][j] * p.scale;
      if (p.bias)
        v += dyn ? (double)bf2f(((const unsigned short*)p.bias)[n])
                 : (double)((const float*)p.bias)[n];
      if (addb) v += (double)addb[(long long)m * p.ldadd + n];
      if (p.relu) v = fmax(v, 0.0);
      Cb[(long long)m * p.ldc + n] = (float)v;  // f32 storage rounding
    }
  }
}

// ---------------------------------------------------------------------------
// Row softmax in-place: f32 storage, f64 internal
// ---------------------------------------------------------------------------
__launch_bounds__(256)
__global__ void row_softmax_k(float* __restrict__ A, int N) {
  long long row = (long long)blockIdx.x * 4 + (threadIdx.x >> 6);
  int lane = threadIdx.x & 63;
  float* a = A + row * N;
  double ev[8];
  int nc = N >> 6;
  double mx = -INFINITY;
  for (int k = 0; k < nc; k++) mx = fmax(mx, (double)a[lane + (k << 6)]);
  for (int off = 32; off; off >>= 1) mx = fmax(mx, __shfl_xor(mx, off, 64));
  double s = 0.0;
  for (int k = 0; k < nc; k++) { double e = exp((double)a[lane + (k << 6)] - mx); ev[k] = e; s += e; }
  for (int off = 32; off; off >>= 1) s += __shfl_xor(s, off, 64);
  double inv = 1.0 / s;
  for (int k = 0; k < nc; k++) a[lane + (k << 6)] = (float)(ev[k] * inv);
}

// ---------------------------------------------------------------------------
// Ms = 0.5*(Aff + Aff^T) -> f32
// ---------------------------------------------------------------------------
__launch_bounds__(256)
__global__ void msym_k(const void* __restrict__ Aff, float* __restrict__ Ms, int d,
                       const int* __restrict__ dflag) {
  int fl = dflag[0];
  int idx = blockIdx.x * 256 + threadIdx.x;
  if (idx < d * d) {
    int i = idx / d, j = idx - i * d;
    double a, b;
    if (fl) {
      a = (double)bf2f(((const unsigned short*)Aff)[idx]);
      b = (double)bf2f(((const unsigned short*)Aff)[j * d + i]);
    } else {
      a = (double)((const float*)Aff)[idx];
      b = (double)((const float*)Aff)[j * d + i];
    }
    Ms[idx] = (float)(0.5 * (a + b));
  }
}

// ---------------------------------------------------------------------------
// Sinkhorn (padded RPM), log-domain fixed point: S f32, u/v f64, P f32.
// ---------------------------------------------------------------------------
__launch_bounds__(256)
__global__ void sink_u_k(const float* __restrict__ S, const double* __restrict__ V,
                         double* __restrict__ U, int N) {
  extern __shared__ double vsh[];
  int b = blockIdx.y;
  const float* Sb = S + (long long)b * N * N;
  const double* Vb = V + (long long)b * N;
  int tid = threadIdx.x, lane = tid & 63, wv = tid >> 6;
  for (int c = tid; c < N; c += 256) vsh[c] = Vb[c];
  __syncthreads();
  int row = blockIdx.x * 4 + wv;
  const float* Sr = Sb + (long long)row * N;
  double m = (lane == 0) ? 0.0 : -INFINITY;
  double s = (lane == 0) ? 1.0 : 0.0;
  for (int c = lane; c < N; c += 64) {
    double x = (double)Sr[c] - vsh[c];
    if (x > m) { s = s * exp(m - x) + 1.0; m = x; }
    else s += exp(x - m);
  }
  for (int off = 32; off; off >>= 1) {
    double mo = __shfl_xor(m, off, 64);
    double so = __shfl_xor(s, off, 64);
    double mm = fmax(m, mo);
    s = s * exp(m - mm) + so * exp(mo - mm);
    m = mm;
  }
  if (lane == 0) U[(long long)b * N + row] = m + log(s);
}

__launch_bounds__(256)
__global__ void sink_v_k(const float* __restrict__ S, const double* __restrict__ U,
                         double* __restrict__ V, int N) {
  extern __shared__ double ush[];
  double* mred = ush + N;
  double* sred = mred + 256;
  int b = blockIdx.y;
  const float* Sb = S + (long long)b * N * N;
  int tid = threadIdx.x, cl = tid & 63, rg = tid >> 6;
  int c = blockIdx.x * 64 + cl;
  for (int i = tid; i < N; i += 256) ush[i] = U[(long long)b * N + i];
  __syncthreads();
  double m = (rg == 0) ? 0.0 : -INFINITY;
  double s = (rg == 0) ? 1.0 : 0.0;
  for (int i = rg; i < N; i += 4) {
    double x = (double)Sb[(long long)i * N + c] - ush[i];
    if (x > m) { s = s * exp(m - x) + 1.0; m = x; }
    else s += exp(x - m);
  }
  mred[rg * 64 + cl] = m; sred[rg * 64 + cl] = s;
  __syncthreads();
  if (rg == 0) {
#pragma unroll
    for (int g = 1; g < 4; g++) {
      double mo = mred[g * 64 + cl], so = sred[g * 64 + cl];
      double mm = fmax(m, mo);
      s = s * exp(m - mm) + so * exp(mo - mm);
      m = mm;
    }
    V[(long long)b * N + c] = m + log(s);
  }
}

__launch_bounds__(256)
__global__ void sink_p_k(const float* __restrict__ S, const double* __restrict__ U,
                         const double* __restrict__ V, float* __restrict__ P, int N) {
  int b = blockIdx.y;
  long long base = (long long)b * N * N;
  const double* Ub = U + (long long)b * N;
  const double* Vb = V + (long long)b * N;
  for (long long e = (long long)blockIdx.x * 256 + threadIdx.x; e < (long long)N * N;
       e += (long long)gridDim.x * 256) {
    int i = (int)(e / N), j = (int)(e - (long long)i * N);
    P[base + e] = (float)exp((double)S[base + e] - Ub[i] - Vb[j]);  // f32 storage
  }
}

// ---------------------------------------------------------------------------
// Top-k pooling: f64 math on f32-stored emb; FINAL SCORE ROUNDED TO F32
// (emulates the reference's f32 score array; sub-ulp boundary pairs tie and
// resolve by lower index, matching jax.lax.top_k).
// ---------------------------------------------------------------------------
__launch_bounds__(256)
__global__ void colstats_k(const float* __restrict__ emb, double* __restrict__ stats, int N, int d) {
  int g = blockIdx.y;
  int cl = threadIdx.x & 63;
  int c = blockIdx.x * 64 + cl;
  int rg = threadIdx.x >> 6;
  const float* e = emb + (long long)g * N * d;
  __shared__ double redm[4][64];
  __shared__ double reds[4][64];
  double mx = -INFINITY;
  for (int r = rg; r < N; r += 4) mx = fmax(mx, (double)e[(long long)r * d + c]);
  redm[rg][cl] = mx;
  __syncthreads();
  mx = fmax(fmax(redm[0][cl], redm[1][cl]), fmax(redm[2][cl], redm[3][cl]));
  __syncthreads();
  double s = 0.0;
  for (int r = rg; r < N; r += 4) s += exp((double)e[(long long)r * d + c] - mx);
  reds[rg][cl] = s;
  __syncthreads();
  if (rg == 0) {
    s = reds[0][cl] + reds[1][cl] + reds[2][cl] + reds[3][cl];
    stats[((long long)g * d + c) * 2] = mx;
    stats[((long long)g * d + c) * 2 + 1] = 1.0 / s;
  }
}

__launch_bounds__(256)
__global__ void score_k(const float* __restrict__ emb, const double* __restrict__ stats,
                        double* __restrict__ score, int N, int d) {
  int g = blockIdx.y;
  int r = blockIdx.x * 64 + (threadIdx.x >> 2);
  int sub = threadIdx.x & 3;
  const float* e = emb + ((long long)g * N + r) * d;
  const double* st = stats + (long long)g * d * 2;
  double s = 0.0;
  for (int c = sub; c < d; c += 4) s += exp((double)e[c] - st[2 * c]) * st[2 * c + 1];
  s += __shfl_down(s, 2, 4);
  s += __shfl_down(s, 1, 4);
  if (sub == 0) score[(long long)g * N + r] = (double)(float)s;  // f32 rounding
}

__launch_bounds__(256)
__global__ void topk_sort_k(const double* __restrict__ score, int* __restrict__ SIDX,
                            int N, int k) {
  __shared__ double sv[1024];
  __shared__ int si[1024];
  int g = blockIdx.x, tid = threadIdx.x;
  (void)k;
  for (int i = tid; i < N; i += 256) { sv[i] = score[(long long)g * N + i]; si[i] = i; }
  __syncthreads();
  for (int kk = 2; kk <= N; kk <<= 1) {
    for (int j = kk >> 1; j > 0; j >>= 1) {
      for (int i = tid; i < N; i += 256) {
        int ixj = i ^ j;
        if (ixj > i) {
          double v1 = sv[i], v2 = sv[ixj];
          int x1 = si[i], x2 = si[ixj];
          bool gtr = (v1 < v2) || (v1 == v2 && x1 > x2);
          bool up = ((i & kk) == 0);
          if (gtr == up) { sv[i] = v2; sv[ixj] = v1; si[i] = x2; si[ixj] = x1; }
        }
      }
      __syncthreads();
    }
  }
  for (int i = tid; i < N; i += 256) SIDX[(long long)g * N + i] = si[i];
}

__launch_bounds__(256)
__global__ void gather_k(const int* __restrict__ SIDX, const float* __restrict__ emb,
                         float* __restrict__ out, int N, int d, int k) {
  int g = blockIdx.x, tid = threadIdx.x;
  for (long long e = tid; e < (long long)k * d; e += 256) {
    int r = (int)(e / d), c = (int)(e - (long long)r * d);
    out[(long long)g * k * d + e] = emb[((long long)g * N + SIDX[(long long)g * N + r]) * d + c];
  }
}

// output converter: f32 -> bf16/f32 per flag
__launch_bounds__(256)
__global__ void cvt_out_k(const float* __restrict__ src, void* __restrict__ dst,
                          long long oofs, int n, const int* __restrict__ dflag) {
  int fl = dflag[0];
  int i = blockIdx.x * 256 + threadIdx.x;
  if (i < n) {
    float v = src[i];
    if (fl) ((__hip_bfloat16*)dst)[oofs + i] = __float2bfloat16(v);
    else ((float*)dst)[oofs + i] = v;
  }
}

// ---------------------------------------------------------------------------
// Host orchestration — f32 arena, ws_size-adaptive pair batching.
// ---------------------------------------------------------------------------
extern "C" void kernel_launch(void* const* d_in, const int* in_sizes, int n_in,
                              void* d_out, int out_size, void* d_ws, size_t ws_size,
                              hipStream_t stream) {
  (void)in_sizes; (void)n_in; (void)out_size;
  static const int NL[3] = {1024, 512, 256};
  static const int DL[3] = {512, 256, 128};
  static const int DINL[3] = {3, 512, 256};
  static const int IWp[3]={0,11,23}, IBp[3]={1,12,24}, IWe[3]={2,13,25}, IBe[3]={3,14,26};
  static const int IWt[3]={-1,15,27};
  static const int IWa[3]={4,16,28}, IBa[3]={5,17,29}, IWu[3]={6,18,30}, IBu[3]={7,19,31};
  static const int IAff[3]={8,20,32}, IWc[3]={9,21,33}, IBc[3]={10,22,34};

  auto Wv = [&](int t) { return (const void*)d_in[4 + t]; };

  float* ws = (float*)d_ws;
  const long long PER_PC = 5257232LL;  // floats per pair
  int pc = 1;
  if (ws_size >= (size_t)(PER_PC * 4 * 4 + 64)) pc = 4;
  else if (ws_size >= (size_t)(PER_PC * 2 * 4 + 64)) pc = 2;

  float* A0 = ws;
  float* B0 = A0 + 2097152LL * pc;
  float* C0 = B0 + 1048576LL * pc;
  float* D0 = C0 + 1048576LL * pc;
  float* IN = D0 + 524288LL * pc;
  double* ST = (double*)(IN + 524288LL * pc);  // 2048*pc doubles
  double* SC = ST + 2048LL * pc;               // 2048*pc doubles
  double* SU = SC + 2048LL * pc;               // 1024*pc doubles
  double* SV = SU + 1024LL * pc;               // 1024*pc doubles
  int* SIDX = (int*)(SV + 1024LL * pc);        // 2048*pc ints
  int* FLAG = SIDX + 2048LL * pc;

  detect_dtype_k<<<dim3(1), dim3(64), 0, stream>>>((const unsigned short*)d_in[0], FLAG);

  GemmP p_;
  auto gemm = [&](const void* A, long long aoff, long long sA, int lda, int tA, int adin,
                  const void* B, long long boff, long long sB, int ldb, int tB, int bdin,
                  const float* A2, int lda2,
                  const void* B2, long long b2off, int ldb2, int K2, int b2din,
                  const void* bias, const float* add, int ldadd,
                  float* C, long long sC, int ldc, int M, int Nc, int K,
                  double scale, int relu, int batches) {
    p_.dflag = FLAG;
    p_.A = A; p_.aoff = aoff; p_.sA = sA; p_.lda = lda; p_.tA = tA; p_.adin = adin;
    p_.B = B; p_.boff = boff; p_.sB = sB; p_.ldb = ldb; p_.tB = tB; p_.bdin = bdin;
    p_.A2 = A2; p_.lda2 = lda2;
    p_.B2 = B2; p_.b2off = b2off; p_.ldb2 = ldb2; p_.K2 = K2; p_.b2din = b2din;
    p_.bias = bias; p_.add = add; p_.ldadd = ldadd;
    p_.C = C; p_.sC = sC; p_.ldc = ldc; p_.M = M; p_.Nc = Nc; p_.K = K;
    p_.scale = scale; p_.relu = relu;
    dim3 grid((Nc + 63) / 64, (M + 63) / 64, batches);
    gemm_fx<<<grid, dim3(256), 0, stream>>>(p_);
  };

  for (int p0 = 0; p0 < 4; p0 += pc) {
    const int s = 2 * pc;
    for (int L = 0; L < 3; L++) {
      int N = NL[L], d = DL[L], din = DINL[L];
      long long ns = (long long)N * d, NN = (long long)N * N;
      int sN = s * N, pcN = pc * N;
      float* X2 = A0;
      float* H = B0;
      float* X3 = C0;
      float* Af = D0;
      float* Spt = A0;
      float* Ppt = A0 + (long long)pc * NN;
      float* G = B0;
      float* MSp = B0 + (long long)pc * ns;
      float* Y = B0;
      float* EMB = A0;

      if (L == 0) {
        long long poff = (long long)p0 * N * 3;
        float* X2t = X2 + (long long)pcN * 2 * d;
        gemm(d_in[0],poff,0,3,0,1, Wv(IWp[0]),0,0,d,0,1, nullptr,0, nullptr,0,0,0,0,
             Wv(IBp[0]), nullptr,0, X2, 0, 2*d, pcN, d, 3, 1.0, 1, 1);
        gemm(d_in[0],poff,0,3,0,1, Wv(IWe[0]),0,0,d,0,1, nullptr,0, nullptr,0,0,0,0,
             Wv(IBe[0]), nullptr,0, X2 + d, 0, 2*d, pcN, d, 3, 1.0, 1, 1);
        gemm(d_in[1],poff,0,3,0,1, Wv(IWp[0]),0,0,d,0,1, nullptr,0, nullptr,0,0,0,0,
             Wv(IBp[0]), nullptr,0, X2t, 0, 2*d, pcN, d, 3, 1.0, 1, 1);
        gemm(d_in[1],poff,0,3,0,1, Wv(IWe[0]),0,0,d,0,1, nullptr,0, nullptr,0,0,0,0,
             Wv(IBe[0]), nullptr,0, X2t + d, 0, 2*d, pcN, d, 3, 1.0, 1, 1);
      } else {
        gemm(IN,0,0,din,0,0, Wv(IWp[L]),0,0,d,0,1, nullptr,0, nullptr,0,0,0,0,
             Wv(IBp[L]), nullptr,0, X2, 0, 2*d, sN, d, din, 1.0, 1, 1);
        gemm(IN,0,0,din,0,0, Wv(IWe[L]),0,0,d,0,1, nullptr,0, nullptr,0,0,0,0,
             Wv(IBe[L]), nullptr,0, X2 + d, 0, 2*d, sN, d, din, 1.0, 1, 1);
      }
      if (L > 0) {
        float* SE = B0;
        double inv = (double)(float)(1.0 / sqrt((double)d));  // np.float32 constant
        gemm(X2,0,0,2*d,0,0, Wv(IWt[L]),0,0,d,0,1, nullptr,0, nullptr,0,0,0,0,
             nullptr, nullptr,0, SE, 0, d, sN, d, 2*d, 1.0, 0, 1);
        gemm(SE,0,ns,d,0,0, SE,0,ns,d,1,0, nullptr,0, nullptr,0,0,0,0,
             nullptr, nullptr,0, Af, NN, N, N, N, d, inv, 0, s);
        row_softmax_k<<<dim3(sN / 4), dim3(256), 0, stream>>>(Af, N);
      }
      gemm(X2,0,0,2*d,0,0, Wv(IWa[L]),0,0,d,0,1, nullptr,0, nullptr,0,0,0,0,
           Wv(IBa[L]), nullptr,0, H, 0, d, sN, d, 2*d, 1.0, 0, 1);
      if (L == 0) {
        gemm(d_in[2],(long long)p0*NN,NN,N,0,1, H,0,ns,d,0,0, nullptr,0, nullptr,0,0,0,0,
             nullptr, nullptr,0, X3, ns, d, N, d, N, 1.0, 0, pc);
        gemm(d_in[3],(long long)p0*NN,NN,N,0,1, H + (long long)pc*ns,0,ns,d,0,0, nullptr,0, nullptr,0,0,0,0,
             nullptr, nullptr,0, X3 + (long long)pc*ns, ns, d, N, d, N, 1.0, 0, pc);
      } else {
        gemm(Af,0,NN,N,0,0, H,0,ns,d,0,0, nullptr,0, nullptr,0,0,0,0,
             nullptr, nullptr,0, X3, ns, d, N, d, N, 1.0, 0, s);
      }
      gemm(X2,0,0,2*d,0,0, Wv(IWu[L]),0,0,d,0,1, nullptr,0, nullptr,0,0,0,0,
           Wv(IBu[L]), X3,d, X3, 0, d, sN, d, 2*d, 1.0, 1, 1);
      msym_k<<<dim3((d * d + 255) / 256), dim3(256), 0, stream>>>(Wv(IAff[L]), MSp, d, FLAG);
      gemm(X3 + (long long)pc*ns,0,0,d,0,0, MSp,0,0,d,0,0, nullptr,0, nullptr,0,0,0,0,
           nullptr, nullptr,0, G, 0, d, pcN, d, d, 1.0, 0, 1);
      gemm(X3,0,ns,d,0,0, G,0,ns,d,1,0, nullptr,0, nullptr,0,0,0,0,
           nullptr, nullptr,0, Spt, NN, N, N, N, d, 1.0, 0, pc);
      hipMemsetAsync(SV, 0, (size_t)pc * N * sizeof(double), stream);
      for (int it = 0; it < 20; it++) {
        sink_u_k<<<dim3(N / 4, pc), dim3(256), N * sizeof(double), stream>>>(Spt, SV, SU, N);
        sink_v_k<<<dim3(N / 64, pc), dim3(256), (N + 512) * sizeof(double), stream>>>(Spt, SU, SV, N);
      }
      sink_p_k<<<dim3(256, pc), dim3(256), 0, stream>>>(Spt, SU, SV, Ppt, N);
      if (L == 2) {
        int on = pc * 65536;
        cvt_out_k<<<dim3((on + 255) / 256), dim3(256), 0, stream>>>(
            Ppt, d_out, (long long)p0 * 65536, on, FLAG);
      } else {
        gemm(Ppt,0,NN,N,0,0, X3 + (long long)pc*ns,0,ns,d,0,0, nullptr,0, nullptr,0,0,0,0,
             nullptr, nullptr,0, Y, ns, d, N, d, N, 1.0, 0, pc);
        gemm(Ppt,0,NN,N,1,0, X3,0,ns,d,0,0, nullptr,0, nullptr,0,0,0,0,
             nullptr, nullptr,0, Y + (long long)pc*ns, ns, d, N, d, N, 1.0, 0, pc);
        gemm(X3,0,0,d,0,0, Wv(IWc[L]),0,0,d,0,1, Y,d, Wv(IWc[L]),(long long)d*d,d,d,1,
             Wv(IBc[L]), nullptr,0, EMB, 0, d, sN, d, d, 1.0, 0, 1);
        colstats_k<<<dim3(d / 64, s), dim3(256), 0, stream>>>(EMB, ST, N, d);
        score_k<<<dim3(N / 64, s), dim3(256), 0, stream>>>(EMB, ST, SC, N, d);
        topk_sort_k<<<dim3(s), dim3(256), 0, stream>>>(SC, SIDX, N, N / 2);
        gather_k<<<dim3(s), dim3(256), 0, stream>>>(SIDX, EMB, IN, N, d, N / 2);
      }
    }
  }
}